// Round 1
// baseline (561.654 us; speedup 1.0000x reference)
//
#include <hip/hip_runtime.h>
#include <math.h>

#define N_NODES 100000
#define N_EDGES 1600000
#define HEADS 8
#define CH 16
#define HC 128            // HEADS*CH
#define NEG_SLOPE 0.2f
#define TOTAL_E (N_EDGES + N_NODES)   // edges + self loops

// ---------------- K1: init degree to 1 (self loop pre-counted) ----------------
__global__ void k_init_deg(int* __restrict__ deg) {
    int i = blockIdx.x * 256 + threadIdx.x;
    if (i < N_NODES) deg[i] = 1;
}

// ---------------- K2: node transform: h = x@W, a_src/a_dst = <h, att> --------
// block=256 handles 2 nodes (128 threads each, one per output channel)
__global__ __launch_bounds__(256) void k_node(
    const float* __restrict__ x, const float* __restrict__ W,
    const float* __restrict__ att_s, const float* __restrict__ att_d,
    float* __restrict__ h, float* __restrict__ a_src, float* __restrict__ a_dst) {
    __shared__ float sW[16 * HC];
    __shared__ float sx[2][16];
    int t = threadIdx.x;
    for (int i = t; i < 16 * HC; i += 256) sW[i] = W[i];
    int local = t >> 7;          // which of the 2 nodes
    int l = t & 127;             // output channel 0..127
    int node = blockIdx.x * 2 + local;
    if (l < 16 && node < N_NODES) sx[local][l] = x[node * 16 + l];
    __syncthreads();
    if (node >= N_NODES) return;
    float acc = 0.f;
#pragma unroll
    for (int k = 0; k < 16; ++k) acc = fmaf(sx[local][k], sW[k * HC + l], acc);
    h[node * HC + l] = acc;
    int c = l & 15;
    float ps = acc * att_s[l];   // att is [H,C] row-major == flat[l]
    float pd = acc * att_d[l];
    // reduce over the 16 channels of a head (contiguous lanes within wave)
#pragma unroll
    for (int off = 8; off >= 1; off >>= 1) {
        ps += __shfl_xor(ps, off);
        pd += __shfl_xor(pd, off);
    }
    if (c == 0) {
        int hd = l >> 4;
        a_src[node * HEADS + hd] = ps;
        a_dst[node * HEADS + hd] = pd;
    }
}

// ---------------- K3: count in-degree -----------------------------------------
__global__ void k_count(const int* __restrict__ ei, int* __restrict__ deg) {
    int e = blockIdx.x * 256 + threadIdx.x;
    if (e < N_EDGES) atomicAdd(&deg[ei[N_EDGES + e]], 1);
}

// ---------------- K4: per-block exclusive scan (256 elems/block) ---------------
__global__ void k_scan_block(const int* __restrict__ deg, int* __restrict__ offsets,
                             int* __restrict__ bsums) {
    __shared__ int s[256];
    int t = threadIdx.x;
    int i = blockIdx.x * 256 + t;
    int v = (i < N_NODES) ? deg[i] : 0;
    s[t] = v;
    __syncthreads();
    for (int off = 1; off < 256; off <<= 1) {
        int y = (t >= off) ? s[t - off] : 0;
        __syncthreads();
        if (t >= off) s[t] += y;
        __syncthreads();
    }
    if (i < N_NODES) offsets[i] = s[t] - v;   // exclusive within block
    if (t == 255) bsums[blockIdx.x] = s[255]; // block total
}

// ---------------- K5: scan of block sums (single block, nb<=512) ---------------
__global__ void k_scan_top(int* __restrict__ bsums, int nb) {
    __shared__ int s[512];
    int t = threadIdx.x;
    int v = (t < nb) ? bsums[t] : 0;
    s[t] = v;
    __syncthreads();
    for (int off = 1; off < 512; off <<= 1) {
        int y = (t >= off) ? s[t - off] : 0;
        __syncthreads();
        if (t >= off) s[t] += y;
        __syncthreads();
    }
    if (t < nb) bsums[t] = s[t] - v;          // exclusive
}

// ---------------- K6: finalize offsets + init cursor ---------------------------
__global__ void k_finalize(int* __restrict__ offsets, const int* __restrict__ bsums,
                           int* __restrict__ cursor) {
    int i = blockIdx.x * 256 + threadIdx.x;
    if (i < N_NODES) {
        int o = offsets[i] + bsums[i >> 8];
        offsets[i] = o;
        cursor[i] = o;
    }
    if (i == 0) offsets[N_NODES] = TOTAL_E;
}

// ---------------- K7: scatter edges into CSR slots -----------------------------
__global__ void k_scatter(const int* __restrict__ ei, int* __restrict__ cursor,
                          int* __restrict__ csr_src) {
    int e = blockIdx.x * 256 + threadIdx.x;
    if (e >= TOTAL_E) return;
    int s, d;
    if (e < N_EDGES) { s = ei[e]; d = ei[N_EDGES + e]; }
    else             { s = e - N_EDGES; d = s; }      // self loop
    int pos = atomicAdd(&cursor[d], 1);
    csr_src[pos] = s;
}

// ---------------- K8: gather + softmax-avg + bias/relu + FC + log_softmax ------
// one 128-thread block per destination node; thread t = head(t>>4), ch(t&15)
__global__ __launch_bounds__(128) void k_gather(
    const float* __restrict__ h, const float* __restrict__ a_src,
    const float* __restrict__ a_dst, const int* __restrict__ offsets,
    const int* __restrict__ csr_src, const float* __restrict__ bias,
    const float* __restrict__ fc_w, const float* __restrict__ fc_b,
    float* __restrict__ out) {
    int d = blockIdx.x;
    int t = threadIdx.x;
    int hd = t >> 4;
    int beg = offsets[d], end = offsets[d + 1];
    float ad = a_dst[d * HEADS + hd];
    float acc = 0.f, wsum = 0.f;
    int s_cur = csr_src[beg];                  // deg >= 1 (self loop)
    for (int j = beg; j < end; ++j) {
        int s_next = (j + 1 < end) ? csr_src[j + 1] : 0;  // prefetch
        float e = a_src[s_cur * HEADS + hd] + ad;
        float lr = e > 0.f ? e : NEG_SLOPE * e;
        float w = __expf(lr);                  // no max-shift needed: |e| <~ 2.5
        acc = fmaf(w, h[s_cur * HC + t], acc);
        wsum += w;
        s_cur = s_next;
    }
    // softmax-weighted average == sum(alpha * h)
    float ov = acc / (wsum + 1e-16f) + bias[t];
    ov = fmaxf(ov, 0.f);
    // FC 128->5: per-thread partials, wave reduce, cross-wave via LDS
    float p[5];
#pragma unroll
    for (int j = 0; j < 5; ++j) p[j] = ov * fc_w[t * 5 + j];
#pragma unroll
    for (int off = 32; off >= 1; off >>= 1) {
#pragma unroll
        for (int j = 0; j < 5; ++j) p[j] += __shfl_xor(p[j], off);
    }
    __shared__ float part[2][5];
    __shared__ float slog[5];
    if ((t & 63) == 0) {
#pragma unroll
        for (int j = 0; j < 5; ++j) part[t >> 6][j] = p[j];
    }
    __syncthreads();
    if (t < 5) slog[t] = part[0][t] + part[1][t] + fc_b[t];
    __syncthreads();
    if (t < 5) {
        float m = slog[0];
#pragma unroll
        for (int j = 1; j < 5; ++j) m = fmaxf(m, slog[j]);
        float sum = 0.f;
#pragma unroll
        for (int j = 0; j < 5; ++j) sum += expf(slog[j] - m);
        out[d * 5 + t] = slog[t] - m - logf(sum);
    }
}

extern "C" void kernel_launch(void* const* d_in, const int* in_sizes, int n_in,
                              void* d_out, int out_size, void* d_ws, size_t ws_size,
                              hipStream_t stream) {
    const float* x     = (const float*)d_in[0];
    const int*   ei    = (const int*)d_in[1];     // [2, E] int32
    const float* W     = (const float*)d_in[2];
    const float* att_s = (const float*)d_in[3];
    const float* att_d = (const float*)d_in[4];
    const float* bias  = (const float*)d_in[5];
    const float* fc_w  = (const float*)d_in[6];
    const float* fc_b  = (const float*)d_in[7];
    float* out = (float*)d_out;

    // workspace carve-up (256B aligned), total ~66 MB
    char* ws = (char*)d_ws;
    size_t off = 0;
    auto carve = [&](size_t bytes) {
        void* p = ws + off;
        off = (off + bytes + 255) & ~(size_t)255;
        return p;
    };
    float* h       = (float*)carve((size_t)N_NODES * HC * 4);
    float* a_src   = (float*)carve((size_t)N_NODES * HEADS * 4);
    float* a_dst   = (float*)carve((size_t)N_NODES * HEADS * 4);
    int*   deg     = (int*)  carve((size_t)N_NODES * 4);
    int*   offsets = (int*)  carve((size_t)(N_NODES + 1) * 4);
    int*   cursor  = (int*)  carve((size_t)N_NODES * 4);
    int*   bsums   = (int*)  carve(512 * 4);
    int*   csr_src = (int*)  carve((size_t)TOTAL_E * 4);

    const int nb_scan = (N_NODES + 255) / 256;   // 391

    k_init_deg<<<(N_NODES + 255) / 256, 256, 0, stream>>>(deg);
    k_node<<<(N_NODES + 1) / 2, 256, 0, stream>>>(x, W, att_s, att_d, h, a_src, a_dst);
    k_count<<<(N_EDGES + 255) / 256, 256, 0, stream>>>(ei, deg);
    k_scan_block<<<nb_scan, 256, 0, stream>>>(deg, offsets, bsums);
    k_scan_top<<<1, 512, 0, stream>>>(bsums, nb_scan);
    k_finalize<<<(N_NODES + 255) / 256, 256, 0, stream>>>(offsets, bsums, cursor);
    k_scatter<<<(TOTAL_E + 255) / 256, 256, 0, stream>>>(ei, cursor, csr_src);
    k_gather<<<N_NODES, 128, 0, stream>>>(h, a_src, a_dst, offsets, csr_src,
                                          bias, fc_w, fc_b, out);
}

// Round 2
// 402.828 us; speedup vs baseline: 1.3943x; 1.3943x over previous
//
#include <hip/hip_runtime.h>
#include <hip/hip_bf16.h>
#include <math.h>

#define N_NODES 100000
#define N_EDGES 1600000
#define HEADS 8
#define CH 16
#define HC 128            // HEADS*CH
#define NEG_SLOPE 0.2f
#define TOTAL_E (N_EDGES + N_NODES)   // edges + self loops

// ---------------- K1: init degree to 1 (self loop pre-counted) ----------------
__global__ void k_init_deg(int* __restrict__ deg) {
    int i = blockIdx.x * 256 + threadIdx.x;
    if (i < N_NODES) deg[i] = 1;
}

// ---------------- K2: node transform: h = x@W (bf16), a_src/a_dst --------------
// wave-autonomous: each wave handles one node per iteration (2 channels/lane).
// W staged in LDS once per block; grid-stride over nodes.
__global__ __launch_bounds__(256) void k_node(
    const float* __restrict__ x, const float* __restrict__ W,
    const float* __restrict__ att_s, const float* __restrict__ att_d,
    __hip_bfloat162* __restrict__ h, float* __restrict__ a_src,
    float* __restrict__ a_dst) {
    __shared__ float sW[16 * HC];
    int t = threadIdx.x;
    for (int i = t; i < 16 * HC; i += 256) sW[i] = W[i];
    __syncthreads();
    int lane = t & 63;
    int gw = blockIdx.x * 4 + (t >> 6);      // global wave id
    int nw = gridDim.x * 4;
    int c0 = 2 * lane;                        // this lane's two channels
    float as0 = att_s[c0], as1 = att_s[c0 + 1];
    float ad0 = att_d[c0], ad1 = att_d[c0 + 1];
    for (int node = gw; node < N_NODES; node += nw) {
        float xv = 0.f;
        if (lane < 16) xv = x[node * 16 + lane];
        float acc0 = 0.f, acc1 = 0.f;
#pragma unroll
        for (int k = 0; k < 16; ++k) {
            float xk = __shfl(xv, k);
            acc0 = fmaf(xk, sW[k * HC + c0], acc0);
            acc1 = fmaf(xk, sW[k * HC + c0 + 1], acc1);
        }
        h[node * 64 + lane] = __float22bfloat162_rn(float2{acc0, acc1});
        float ps = acc0 * as0 + acc1 * as1;
        float pd = acc0 * ad0 + acc1 * ad1;
        // reduce over the 8 lanes of one head (c0 spans 2 ch, 8 lanes/head)
#pragma unroll
        for (int off = 4; off >= 1; off >>= 1) {
            ps += __shfl_xor(ps, off);
            pd += __shfl_xor(pd, off);
        }
        if ((lane & 7) == 0) {
            int hd = lane >> 3;
            a_src[node * HEADS + hd] = ps;
            a_dst[node * HEADS + hd] = pd;
        }
    }
}

// ---------------- K3: count in-degree -----------------------------------------
__global__ void k_count(const int* __restrict__ ei, int* __restrict__ deg) {
    int e = blockIdx.x * 256 + threadIdx.x;
    if (e < N_EDGES) atomicAdd(&deg[ei[N_EDGES + e]], 1);
}

// ---------------- K4: per-block exclusive scan (256 elems/block) ---------------
__global__ void k_scan_block(const int* __restrict__ deg, int* __restrict__ offsets,
                             int* __restrict__ bsums) {
    __shared__ int s[256];
    int t = threadIdx.x;
    int i = blockIdx.x * 256 + t;
    int v = (i < N_NODES) ? deg[i] : 0;
    s[t] = v;
    __syncthreads();
    for (int off = 1; off < 256; off <<= 1) {
        int y = (t >= off) ? s[t - off] : 0;
        __syncthreads();
        if (t >= off) s[t] += y;
        __syncthreads();
    }
    if (i < N_NODES) offsets[i] = s[t] - v;   // exclusive within block
    if (t == 255) bsums[blockIdx.x] = s[255]; // block total
}

// ---------------- K5: scan of block sums (single block, nb<=512) ---------------
__global__ void k_scan_top(int* __restrict__ bsums, int nb) {
    __shared__ int s[512];
    int t = threadIdx.x;
    int v = (t < nb) ? bsums[t] : 0;
    s[t] = v;
    __syncthreads();
    for (int off = 1; off < 512; off <<= 1) {
        int y = (t >= off) ? s[t - off] : 0;
        __syncthreads();
        if (t >= off) s[t] += y;
        __syncthreads();
    }
    if (t < nb) bsums[t] = s[t] - v;          // exclusive
}

// ---------------- K6: finalize offsets + init cursor ---------------------------
__global__ void k_finalize(int* __restrict__ offsets, const int* __restrict__ bsums,
                           int* __restrict__ cursor) {
    int i = blockIdx.x * 256 + threadIdx.x;
    if (i < N_NODES) {
        int o = offsets[i] + bsums[i >> 8];
        offsets[i] = o;
        cursor[i] = o;
    }
    if (i == 0) offsets[N_NODES] = TOTAL_E;
}

// ---------------- K7: scatter edges into CSR slots -----------------------------
__global__ void k_scatter(const int* __restrict__ ei, int* __restrict__ cursor,
                          int* __restrict__ csr_src) {
    int e = blockIdx.x * 256 + threadIdx.x;
    if (e >= TOTAL_E) return;
    int s, d;
    if (e < N_EDGES) { s = ei[e]; d = ei[N_EDGES + e]; }
    else             { s = e - N_EDGES; d = s; }      // self loop
    int pos = atomicAdd(&cursor[d], 1);
    csr_src[pos] = s;
}

// ---------------- K8: gather + softmax-avg + bias/relu + FC + log_softmax ------
// 32 threads per node (4 channels each, bf16x4 = 8B loads); 8 nodes / 256-block.
__global__ __launch_bounds__(256) void k_gather(
    const __hip_bfloat162* __restrict__ h, const float* __restrict__ a_src,
    const float* __restrict__ a_dst, const int* __restrict__ offsets,
    const int* __restrict__ csr_src, const float* __restrict__ bias,
    const float* __restrict__ fc_w, const float* __restrict__ fc_b,
    float* __restrict__ out) {
    int t = threadIdx.x;
    int q = t & 31;                    // lane within node group
    int d = blockIdx.x * 8 + (t >> 5);
    if (d >= N_NODES) return;
    int head = q >> 2;
    int c0 = q * 4;                    // first of this thread's 4 channels
    int beg = offsets[d], end = offsets[d + 1];
    float ad = a_dst[d * HEADS + head];
    float acc0 = 0.f, acc1 = 0.f, acc2 = 0.f, acc3 = 0.f, wsum = 0.f;
    int s = csr_src[beg];              // deg >= 1 (self loop)
    for (int j = beg; j < end; ++j) {
        int s_nx = (j + 1 < end) ? csr_src[j + 1] : s;  // prefetch
        float e = a_src[s * HEADS + head] + ad;
        float lr = e > 0.f ? e : NEG_SLOPE * e;
        float w = __expf(lr);          // no max-shift: |e| <~ 3 in-distribution
        union { uint2 u; __hip_bfloat162 b[2]; } cv;
        cv.u = *(const uint2*)(h + (size_t)s * 64 + q * 2);  // 8B = 4 bf16 ch
        float2 f01 = __bfloat1622float2(cv.b[0]);
        float2 f23 = __bfloat1622float2(cv.b[1]);
        acc0 = fmaf(w, f01.x, acc0);
        acc1 = fmaf(w, f01.y, acc1);
        acc2 = fmaf(w, f23.x, acc2);
        acc3 = fmaf(w, f23.y, acc3);
        wsum += w;
        s = s_nx;
    }
    float inv = 1.f / (wsum + 1e-16f);
    float ov0 = fmaxf(fmaf(acc0, inv, 0.f) + bias[c0 + 0], 0.f);
    float ov1 = fmaxf(fmaf(acc1, inv, 0.f) + bias[c0 + 1], 0.f);
    float ov2 = fmaxf(fmaf(acc2, inv, 0.f) + bias[c0 + 2], 0.f);
    float ov3 = fmaxf(fmaf(acc3, inv, 0.f) + bias[c0 + 3], 0.f);
    // FC 128->5: partials over this thread's 4 channels, reduce over 32 lanes
    float p[5];
#pragma unroll
    for (int j = 0; j < 5; ++j) {
        p[j] = ov0 * fc_w[(c0 + 0) * 5 + j] + ov1 * fc_w[(c0 + 1) * 5 + j]
             + ov2 * fc_w[(c0 + 2) * 5 + j] + ov3 * fc_w[(c0 + 3) * 5 + j];
    }
#pragma unroll
    for (int off = 16; off >= 1; off >>= 1) {
#pragma unroll
        for (int j = 0; j < 5; ++j) p[j] += __shfl_xor(p[j], off);
    }
    if (q == 0) {
        float l[5], m = -1e30f;
#pragma unroll
        for (int j = 0; j < 5; ++j) { l[j] = p[j] + fc_b[j]; m = fmaxf(m, l[j]); }
        float sum = 0.f;
#pragma unroll
        for (int j = 0; j < 5; ++j) sum += __expf(l[j] - m);
        float ls = m + __logf(sum);
#pragma unroll
        for (int j = 0; j < 5; ++j) out[d * 5 + j] = l[j] - ls;
    }
}

extern "C" void kernel_launch(void* const* d_in, const int* in_sizes, int n_in,
                              void* d_out, int out_size, void* d_ws, size_t ws_size,
                              hipStream_t stream) {
    const float* x     = (const float*)d_in[0];
    const int*   ei    = (const int*)d_in[1];     // [2, E] int32
    const float* W     = (const float*)d_in[2];
    const float* att_s = (const float*)d_in[3];
    const float* att_d = (const float*)d_in[4];
    const float* bias  = (const float*)d_in[5];
    const float* fc_w  = (const float*)d_in[6];
    const float* fc_b  = (const float*)d_in[7];
    float* out = (float*)d_out;

    // workspace carve-up (256B aligned)
    char* ws = (char*)d_ws;
    size_t off = 0;
    auto carve = [&](size_t bytes) {
        void* p = ws + off;
        off = (off + bytes + 255) & ~(size_t)255;
        return p;
    };
    __hip_bfloat162* h = (__hip_bfloat162*)carve((size_t)N_NODES * HC * 2); // bf16
    float* a_src   = (float*)carve((size_t)N_NODES * HEADS * 4);
    float* a_dst   = (float*)carve((size_t)N_NODES * HEADS * 4);
    int*   deg     = (int*)  carve((size_t)N_NODES * 4);
    int*   offsets = (int*)  carve((size_t)(N_NODES + 1) * 4);
    int*   cursor  = (int*)  carve((size_t)N_NODES * 4);
    int*   bsums   = (int*)  carve(512 * 4);
    int*   csr_src = (int*)  carve((size_t)TOTAL_E * 4);

    const int nb_scan = (N_NODES + 255) / 256;   // 391

    k_init_deg<<<(N_NODES + 255) / 256, 256, 0, stream>>>(deg);
    k_node<<<512, 256, 0, stream>>>(x, W, att_s, att_d, h, a_src, a_dst);
    k_count<<<(N_EDGES + 255) / 256, 256, 0, stream>>>(ei, deg);
    k_scan_block<<<nb_scan, 256, 0, stream>>>(deg, offsets, bsums);
    k_scan_top<<<1, 512, 0, stream>>>(bsums, nb_scan);
    k_finalize<<<(N_NODES + 255) / 256, 256, 0, stream>>>(offsets, bsums, cursor);
    k_scatter<<<(TOTAL_E + 255) / 256, 256, 0, stream>>>(ei, cursor, csr_src);
    k_gather<<<(N_NODES + 7) / 8, 256, 0, stream>>>(h, a_src, a_dst, offsets, csr_src,
                                                    bias, fc_w, fc_b, out);
}

// Round 3
// 349.821 us; speedup vs baseline: 1.6055x; 1.1515x over previous
//
#include <hip/hip_runtime.h>
#include <hip/hip_bf16.h>
#include <math.h>

#define N_NODES 100000
#define N_EDGES 1600000
#define HEADS 8
#define CH 16
#define HC 128
#define NEG_SLOPE 0.2f
#define TOTAL_E (N_EDGES + N_NODES)

#define NB 196            // buckets: dst >> 9, 512 dests each (196*512 >= 100000)
#define DPB 512
#define CAPB 16           // per-bucket LDS buffer entries in k_append
#define CAPS 12288        // per-bucket CSR staging entries in k_build (avg ~8.7K)

// ---------------- K0: zero bucket histogram ------------------------------------
__global__ void k_zero(int* __restrict__ bhist) {
    int t = threadIdx.x;
    if (t < NB) bhist[t] = 0;
}

// ---------------- K1: node transform: h = x@W (bf16), a_src/a_dst --------------
__global__ __launch_bounds__(256) void k_node(
    const float* __restrict__ x, const float* __restrict__ W,
    const float* __restrict__ att_s, const float* __restrict__ att_d,
    __hip_bfloat162* __restrict__ h, float* __restrict__ a_src,
    float* __restrict__ a_dst) {
    __shared__ float sW[16 * HC];
    int t = threadIdx.x;
    for (int i = t; i < 16 * HC; i += 256) sW[i] = W[i];
    __syncthreads();
    int lane = t & 63;
    int gw = blockIdx.x * 4 + (t >> 6);
    int nw = gridDim.x * 4;
    int c0 = 2 * lane;
    float as0 = att_s[c0], as1 = att_s[c0 + 1];
    float ad0 = att_d[c0], ad1 = att_d[c0 + 1];
    for (int node = gw; node < N_NODES; node += nw) {
        float xv = 0.f;
        if (lane < 16) xv = x[node * 16 + lane];
        float acc0 = 0.f, acc1 = 0.f;
#pragma unroll
        for (int k = 0; k < 16; ++k) {
            float xk = __shfl(xv, k);
            acc0 = fmaf(xk, sW[k * HC + c0], acc0);
            acc1 = fmaf(xk, sW[k * HC + c0 + 1], acc1);
        }
        h[node * 64 + lane] = __float22bfloat162_rn(float2{acc0, acc1});
        float ps = acc0 * as0 + acc1 * as1;
        float pd = acc0 * ad0 + acc1 * ad1;
#pragma unroll
        for (int off = 4; off >= 1; off >>= 1) {
            ps += __shfl_xor(ps, off);
            pd += __shfl_xor(pd, off);
        }
        if ((lane & 7) == 0) {
            int hd = lane >> 3;
            a_src[node * HEADS + hd] = ps;
            a_dst[node * HEADS + hd] = pd;
        }
    }
}

// ---------------- K2: bucket histogram of edge destinations --------------------
__global__ __launch_bounds__(256) void k_bhist(const int* __restrict__ ei,
                                               int* __restrict__ bhist) {
    __shared__ int lh[NB];
    int t = threadIdx.x;
    if (t < NB) lh[t] = 0;
    __syncthreads();
    for (int e = blockIdx.x * 256 + t; e < N_EDGES; e += gridDim.x * 256)
        atomicAdd(&lh[ei[N_EDGES + e] >> 9], 1);
    __syncthreads();
    if (t < NB && lh[t]) atomicAdd(&bhist[t], lh[t]);
}

// ---------------- K3: scan bucket counts (+analytic self loops) ----------------
__global__ void k_bscan(const int* __restrict__ bhist, int* __restrict__ bbase,
                        int* __restrict__ gcur, int* __restrict__ offsets) {
    __shared__ int s[256];
    int t = threadIdx.x;
    int selfs = 0, v = 0;
    if (t < NB) {
        int rem = N_NODES - (t << 9);
        selfs = rem < DPB ? rem : DPB;
        v = bhist[t] + selfs;
    }
    s[t] = v;
    __syncthreads();
    for (int off = 1; off < 256; off <<= 1) {
        int y = (t >= off) ? s[t - off] : 0;
        __syncthreads();
        if (t >= off) s[t] += y;
        __syncthreads();
    }
    if (t < NB) {
        int excl = s[t] - v;
        bbase[t] = excl;
        gcur[t] = excl;            // append cursor starts at bucket base
        if (t == NB - 1) bbase[NB] = excl + v;   // == TOTAL_E
    }
    if (t == 0) offsets[N_NODES] = TOTAL_E;
}

// ---------------- K4: LDS-buffered bucket append of (src, dst&511) -------------
__global__ __launch_bounds__(256) void k_append(const int* __restrict__ ei,
                                                int* __restrict__ gcur,
                                                uint2* __restrict__ stg) {
    __shared__ uint2 lbuf[NB][CAPB];
    __shared__ int lcnt[NB];
    int t = threadIdx.x;
    if (t < NB) lcnt[t] = 0;
    __syncthreads();
    int per = (N_EDGES + gridDim.x - 1) / gridDim.x;
    int beg = blockIdx.x * per;
    int end = beg + per; if (end > N_EDGES) end = N_EDGES;
    for (int base = beg; base < end; base += 256) {
        int e = base + t;
        if (e < end) {
            unsigned src = (unsigned)ei[e];
            int dst = ei[N_EDGES + e];
            int b = dst >> 9;
            unsigned loc = (unsigned)(dst & (DPB - 1));
            int idx = atomicAdd(&lcnt[b], 1);
            if (idx < CAPB) lbuf[b][idx] = uint2{src, loc};
            else {                          // rare overflow: direct append
                int gp = atomicAdd(&gcur[b], 1);
                stg[gp] = uint2{src, loc};
            }
        }
        __syncthreads();
        if (t < NB) {
            int n = lcnt[t]; if (n > CAPB) n = CAPB;
            int ng = n & ~7;                // flush 64B groups
            if (ng) {
                int gp = atomicAdd(&gcur[t], ng);
#pragma unroll 1
                for (int i = 0; i < ng; ++i) stg[gp + i] = lbuf[t][i];
                for (int i = 0; i < n - ng; ++i) lbuf[t][i] = lbuf[t][ng + i];
                lcnt[t] = n - ng;
            } else lcnt[t] = n;
        }
        __syncthreads();
    }
    if (t < NB) {                           // final partial flush
        int n = lcnt[t]; if (n > CAPB) n = CAPB;
        if (n) {
            int gp = atomicAdd(&gcur[t], n);
            for (int i = 0; i < n; ++i) stg[gp + i] = lbuf[t][i];
        }
    }
}

// ---------------- K5: per-bucket CSR finalize (one block per bucket) -----------
__global__ __launch_bounds__(256) void k_build(
    const uint2* __restrict__ stg, const int* __restrict__ bbase,
    const int* __restrict__ gcur, int* __restrict__ offsets,
    int* __restrict__ csr_src) {
    __shared__ int hist[DPB];      // becomes cursor after scan
    __shared__ int bs[DPB];        // exclusive local offsets
    __shared__ int ps[256];
    __shared__ int cstage[CAPS];
    int b = blockIdx.x;
    int t = threadIdx.x;
    int ebase = bbase[b];
    int ecnt = gcur[b] - ebase;            // edges appended to this bucket
    int total = bbase[b + 1] - ebase;      // edges + self loops
    bool fits = (total <= CAPS);
    int d0 = b << 9;
    // init hist: 1 per valid dest (the self loop)
    for (int l = t; l < DPB; l += 256) hist[l] = (d0 + l < N_NODES) ? 1 : 0;
    __syncthreads();
    // phase A: histogram of appended edges
    for (int i = t; i < ecnt; i += 256) atomicAdd(&hist[stg[ebase + i].y], 1);
    __syncthreads();
    // phase B: exclusive scan over 512 (pair-sum + 256-scan + expand)
    int h0 = hist[2 * t], h1 = hist[2 * t + 1];
    int pv = h0 + h1;
    ps[t] = pv;
    __syncthreads();
    for (int off = 1; off < 256; off <<= 1) {
        int y = (t >= off) ? ps[t - off] : 0;
        __syncthreads();
        if (t >= off) ps[t] += y;
        __syncthreads();
    }
    int excl = ps[t] - pv;
    bs[2 * t] = excl;
    bs[2 * t + 1] = excl + h0;
    __syncthreads();
    // write offsets, place self loops, init cursors (= base + 1)
    for (int l = t; l < DPB; l += 256) {
        int gd = d0 + l;
        if (gd < N_NODES) {
            int lb = bs[l];
            offsets[gd] = ebase + lb;
            if (fits) cstage[lb] = gd; else csr_src[ebase + lb] = gd;
        }
    }
    __syncthreads();
    for (int l = t; l < DPB; l += 256) hist[l] = bs[l] + 1;  // cursor
    __syncthreads();
    // phase C: place edges
    for (int i = t; i < ecnt; i += 256) {
        uint2 en = stg[ebase + i];
        int pos = atomicAdd(&hist[en.y], 1);
        if (fits) cstage[pos] = (int)en.x; else csr_src[ebase + pos] = (int)en.x;
    }
    __syncthreads();
    // phase D: stream staged CSR slice out coalesced
    if (fits)
        for (int i = t; i < total; i += 256) csr_src[ebase + i] = cstage[i];
}

// ---------------- K6: gather + softmax-avg + bias/relu + FC + log_softmax ------
__global__ __launch_bounds__(256) void k_gather(
    const __hip_bfloat162* __restrict__ h, const float* __restrict__ a_src,
    const float* __restrict__ a_dst, const int* __restrict__ offsets,
    const int* __restrict__ csr_src, const float* __restrict__ bias,
    const float* __restrict__ fc_w, const float* __restrict__ fc_b,
    float* __restrict__ out) {
    int t = threadIdx.x;
    int q = t & 31;
    int d = blockIdx.x * 8 + (t >> 5);
    if (d >= N_NODES) return;
    int head = q >> 2;
    int c0 = q * 4;
    int beg = offsets[d], end = offsets[d + 1];
    float ad = a_dst[d * HEADS + head];
    float acc0 = 0.f, acc1 = 0.f, acc2 = 0.f, acc3 = 0.f, wsum = 0.f;
    int s = csr_src[beg];
    for (int j = beg; j < end; ++j) {
        int s_nx = (j + 1 < end) ? csr_src[j + 1] : s;
        float e = a_src[s * HEADS + head] + ad;
        float lr = e > 0.f ? e : NEG_SLOPE * e;
        float w = __expf(lr);
        union { uint2 u; __hip_bfloat162 bb[2]; } cv;
        cv.u = *(const uint2*)(h + (size_t)s * 64 + q * 2);
        float2 f01 = __bfloat1622float2(cv.bb[0]);
        float2 f23 = __bfloat1622float2(cv.bb[1]);
        acc0 = fmaf(w, f01.x, acc0);
        acc1 = fmaf(w, f01.y, acc1);
        acc2 = fmaf(w, f23.x, acc2);
        acc3 = fmaf(w, f23.y, acc3);
        wsum += w;
        s = s_nx;
    }
    float inv = 1.f / (wsum + 1e-16f);
    float ov0 = fmaxf(acc0 * inv + bias[c0 + 0], 0.f);
    float ov1 = fmaxf(acc1 * inv + bias[c0 + 1], 0.f);
    float ov2 = fmaxf(acc2 * inv + bias[c0 + 2], 0.f);
    float ov3 = fmaxf(acc3 * inv + bias[c0 + 3], 0.f);
    float p[5];
#pragma unroll
    for (int j = 0; j < 5; ++j) {
        p[j] = ov0 * fc_w[(c0 + 0) * 5 + j] + ov1 * fc_w[(c0 + 1) * 5 + j]
             + ov2 * fc_w[(c0 + 2) * 5 + j] + ov3 * fc_w[(c0 + 3) * 5 + j];
    }
#pragma unroll
    for (int off = 16; off >= 1; off >>= 1) {
#pragma unroll
        for (int j = 0; j < 5; ++j) p[j] += __shfl_xor(p[j], off);
    }
    if (q == 0) {
        float l[5], m = -1e30f;
#pragma unroll
        for (int j = 0; j < 5; ++j) { l[j] = p[j] + fc_b[j]; m = fmaxf(m, l[j]); }
        float sum = 0.f;
#pragma unroll
        for (int j = 0; j < 5; ++j) sum += __expf(l[j] - m);
        float ls = m + __logf(sum);
#pragma unroll
        for (int j = 0; j < 5; ++j) out[d * 5 + j] = l[j] - ls;
    }
}

extern "C" void kernel_launch(void* const* d_in, const int* in_sizes, int n_in,
                              void* d_out, int out_size, void* d_ws, size_t ws_size,
                              hipStream_t stream) {
    const float* x     = (const float*)d_in[0];
    const int*   ei    = (const int*)d_in[1];
    const float* W     = (const float*)d_in[2];
    const float* att_s = (const float*)d_in[3];
    const float* att_d = (const float*)d_in[4];
    const float* bias  = (const float*)d_in[5];
    const float* fc_w  = (const float*)d_in[6];
    const float* fc_b  = (const float*)d_in[7];
    float* out = (float*)d_out;

    char* ws = (char*)d_ws;
    size_t off = 0;
    auto carve = [&](size_t bytes) {
        void* p = ws + off;
        off = (off + bytes + 255) & ~(size_t)255;
        return p;
    };
    __hip_bfloat162* h = (__hip_bfloat162*)carve((size_t)N_NODES * HC * 2);
    float* a_src   = (float*)carve((size_t)N_NODES * HEADS * 4);
    float* a_dst   = (float*)carve((size_t)N_NODES * HEADS * 4);
    int*   bhist   = (int*)  carve((NB + 1) * 4);
    int*   bbase   = (int*)  carve((NB + 1) * 4);
    int*   gcur    = (int*)  carve((NB + 1) * 4);
    int*   offsets = (int*)  carve((size_t)(N_NODES + 1) * 4);
    uint2* stg     = (uint2*)carve((size_t)TOTAL_E * 8);
    int*   csr_src = (int*)  carve((size_t)TOTAL_E * 4);

    k_zero<<<1, 256, 0, stream>>>(bhist);
    k_node<<<512, 256, 0, stream>>>(x, W, att_s, att_d, h, a_src, a_dst);
    k_bhist<<<256, 256, 0, stream>>>(ei, bhist);
    k_bscan<<<1, 256, 0, stream>>>(bhist, bbase, gcur, offsets);
    k_append<<<256, 256, 0, stream>>>(ei, gcur, stg);
    k_build<<<NB, 256, 0, stream>>>(stg, bbase, gcur, offsets, csr_src);
    k_gather<<<(N_NODES + 7) / 8, 256, 0, stream>>>(h, a_src, a_dst, offsets, csr_src,
                                                    bias, fc_w, fc_b, out);
}

// Round 4
// 245.457 us; speedup vs baseline: 2.2882x; 1.4252x over previous
//
#include <hip/hip_runtime.h>
#include <hip/hip_bf16.h>
#include <math.h>

#define N_NODES 100000
#define N_EDGES 1600000
#define HEADS 8
#define CH 16
#define HC 128
#define NEG_SLOPE 0.2f
#define TOTAL_E (N_EDGES + N_NODES)

#define DPB 256                          // dests per bucket
#define NB  ((N_NODES + DPB - 1) / DPB)  // 391 buckets
#define NCH 512                          // edge chunks (1.6M/512 = 3125 exact)
#define EPC ((N_EDGES + NCH - 1) / NCH)
#define CAPS 5120                        // per-bucket CSR stage (max load ~4600)

// ---------------- K1: node transform: h = x@W (bf16), a_src/a_dst --------------
__global__ __launch_bounds__(256) void k_node(
    const float* __restrict__ x, const float* __restrict__ W,
    const float* __restrict__ att_s, const float* __restrict__ att_d,
    __hip_bfloat162* __restrict__ h, float* __restrict__ a_src,
    float* __restrict__ a_dst) {
    __shared__ float sW[16 * HC];
    int t = threadIdx.x;
    for (int i = t; i < 16 * HC; i += 256) sW[i] = W[i];
    __syncthreads();
    int lane = t & 63;
    int gw = blockIdx.x * 4 + (t >> 6);
    int nw = gridDim.x * 4;
    int c0 = 2 * lane;
    float as0 = att_s[c0], as1 = att_s[c0 + 1];
    float ad0 = att_d[c0], ad1 = att_d[c0 + 1];
    for (int node = gw; node < N_NODES; node += nw) {
        float xv = 0.f;
        if (lane < 16) xv = x[node * 16 + lane];
        float acc0 = 0.f, acc1 = 0.f;
#pragma unroll
        for (int k = 0; k < 16; ++k) {
            float xk = __shfl(xv, k);
            acc0 = fmaf(xk, sW[k * HC + c0], acc0);
            acc1 = fmaf(xk, sW[k * HC + c0 + 1], acc1);
        }
        h[node * 64 + lane] = __float22bfloat162_rn(float2{acc0, acc1});
        float ps = acc0 * as0 + acc1 * as1;
        float pd = acc0 * ad0 + acc1 * ad1;
#pragma unroll
        for (int off = 4; off >= 1; off >>= 1) {
            ps += __shfl_xor(ps, off);
            pd += __shfl_xor(pd, off);
        }
        if ((lane & 7) == 0) {
            int hd = lane >> 3;
            a_src[node * HEADS + hd] = ps;
            a_dst[node * HEADS + hd] = pd;
        }
    }
}

// ---------------- K2: per-chunk bucket histogram -------------------------------
__global__ __launch_bounds__(256) void k_hist2d(const int* __restrict__ ei,
                                                int* __restrict__ cnt2d) {
    __shared__ int lh[NB];
    int t = threadIdx.x, c = blockIdx.x;
    for (int b = t; b < NB; b += 256) lh[b] = 0;
    __syncthreads();
    int beg = c * EPC, end = beg + EPC; if (end > N_EDGES) end = N_EDGES;
    for (int e = beg + t; e < end; e += 256)
        atomicAdd(&lh[ei[N_EDGES + e] >> 8], 1);
    __syncthreads();
    for (int b = t; b < NB; b += 256) cnt2d[c * NB + b] = lh[b];
}

// ---------------- K3: per-bucket exclusive scan over chunks (in place) ---------
__global__ __launch_bounds__(512) void k_scan_chunks(int* __restrict__ cnt2d,
                                                     int* __restrict__ etot) {
    __shared__ int s[NCH];
    int b = blockIdx.x, t = threadIdx.x;
    int v = cnt2d[t * NB + b];
    s[t] = v;
    __syncthreads();
    for (int off = 1; off < NCH; off <<= 1) {
        int y = (t >= off) ? s[t - off] : 0;
        __syncthreads();
        if (t >= off) s[t] += y;
        __syncthreads();
    }
    cnt2d[t * NB + b] = s[t] - v;        // exclusive within bucket
    if (t == NCH - 1) etot[b] = s[t];
}

// ---------------- K4: scan bucket totals → staging bases -----------------------
__global__ __launch_bounds__(512) void k_scan_top(const int* __restrict__ etot,
                                                  int* __restrict__ sbase,
                                                  int* __restrict__ offsets) {
    __shared__ int s[512];
    int t = threadIdx.x;
    int v = (t < NB) ? etot[t] : 0;
    s[t] = v;
    __syncthreads();
    for (int off = 1; off < 512; off <<= 1) {
        int y = (t >= off) ? s[t - off] : 0;
        __syncthreads();
        if (t >= off) s[t] += y;
        __syncthreads();
    }
    if (t < NB) {
        sbase[t] = s[t] - v;
        if (t == NB - 1) sbase[NB] = s[t];   // == N_EDGES
    }
    if (t == 0) offsets[N_NODES] = TOTAL_E;
}

// ---------------- K5: direct placement into bucket-partitioned staging ---------
__global__ __launch_bounds__(256) void k_place(const int* __restrict__ ei,
                                               const int* __restrict__ cnt2d,
                                               const int* __restrict__ sbase,
                                               unsigned* __restrict__ stg) {
    __shared__ int cur[NB];
    int t = threadIdx.x, c = blockIdx.x;
    for (int b = t; b < NB; b += 256) cur[b] = sbase[b] + cnt2d[c * NB + b];
    __syncthreads();
    int beg = c * EPC, end = beg + EPC; if (end > N_EDGES) end = N_EDGES;
    for (int e = beg + t; e < end; e += 256) {
        unsigned src = (unsigned)ei[e];
        int dst = ei[N_EDGES + e];
        int pos = atomicAdd(&cur[dst >> 8], 1);
        stg[pos] = ((unsigned)(dst & 255) << 17) | src;   // src < 2^17
    }
}

// ---------------- K6: per-bucket CSR finalize (one block per bucket) -----------
__global__ __launch_bounds__(256) void k_build(const unsigned* __restrict__ stg,
                                               const int* __restrict__ sbase,
                                               int* __restrict__ offsets,
                                               int* __restrict__ csr_src) {
    __shared__ int hist[DPB];     // count → cursor
    __shared__ int bs[DPB];       // scan workspace
    __shared__ int cstage[CAPS];
    int b = blockIdx.x, t = threadIdx.x;
    int sb = sbase[b];
    int ecnt = sbase[b + 1] - sb;
    int d0 = b << 8;
    int gd = d0 + t;
    bool valid = gd < N_NODES;
    int selfc = N_NODES - d0; if (selfc > DPB) selfc = DPB;
    int total = ecnt + selfc;
    bool fits = total <= CAPS;
    int cbase = sb + d0;          // CSR base: earlier buckets' edges + selfs
    hist[t] = valid ? 1 : 0;      // self loop pre-counted
    __syncthreads();
    for (int i = t; i < ecnt; i += 256) atomicAdd(&hist[stg[sb + i] >> 17], 1);
    __syncthreads();
    int pv = hist[t];
    bs[t] = pv;
    __syncthreads();
    for (int off = 1; off < DPB; off <<= 1) {
        int y = (t >= off) ? bs[t - off] : 0;
        __syncthreads();
        if (t >= off) bs[t] += y;
        __syncthreads();
    }
    int excl = bs[t] - pv;
    if (valid) {
        offsets[gd] = cbase + excl;
        if (fits) cstage[excl] = gd; else csr_src[cbase + excl] = gd;  // self loop
    }
    hist[t] = excl + (valid ? 1 : 0);   // cursor past self loop
    __syncthreads();
    for (int i = t; i < ecnt; i += 256) {
        unsigned p = stg[sb + i];
        int pos = atomicAdd(&hist[p >> 17], 1);
        int src = (int)(p & 0x1FFFF);
        if (fits) cstage[pos] = src; else csr_src[cbase + pos] = src;
    }
    __syncthreads();
    if (fits)
        for (int i = t; i < total; i += 256) csr_src[cbase + i] = cstage[i];
}

// ---------------- K7: gather + softmax-avg + bias/relu + FC + log_softmax ------
__global__ __launch_bounds__(256) void k_gather(
    const __hip_bfloat162* __restrict__ h, const float* __restrict__ a_src,
    const float* __restrict__ a_dst, const int* __restrict__ offsets,
    const int* __restrict__ csr_src, const float* __restrict__ bias,
    const float* __restrict__ fc_w, const float* __restrict__ fc_b,
    float* __restrict__ out) {
    int t = threadIdx.x;
    int q = t & 31;
    int d = blockIdx.x * 8 + (t >> 5);
    if (d >= N_NODES) return;
    int head = q >> 2;
    int c0 = q * 4;
    int beg = offsets[d], end = offsets[d + 1];
    float ad = a_dst[d * HEADS + head];
    float acc0 = 0.f, acc1 = 0.f, acc2 = 0.f, acc3 = 0.f, wsum = 0.f;
    int s = csr_src[beg];
    for (int j = beg; j < end; ++j) {
        int s_nx = (j + 1 < end) ? csr_src[j + 1] : s;
        float e = a_src[s * HEADS + head] + ad;
        float lr = e > 0.f ? e : NEG_SLOPE * e;
        float w = __expf(lr);
        union { uint2 u; __hip_bfloat162 bb[2]; } cv;
        cv.u = *(const uint2*)(h + (size_t)s * 64 + q * 2);
        float2 f01 = __bfloat1622float2(cv.bb[0]);
        float2 f23 = __bfloat1622float2(cv.bb[1]);
        acc0 = fmaf(w, f01.x, acc0);
        acc1 = fmaf(w, f01.y, acc1);
        acc2 = fmaf(w, f23.x, acc2);
        acc3 = fmaf(w, f23.y, acc3);
        wsum += w;
        s = s_nx;
    }
    float inv = 1.f / (wsum + 1e-16f);
    float ov0 = fmaxf(acc0 * inv + bias[c0 + 0], 0.f);
    float ov1 = fmaxf(acc1 * inv + bias[c0 + 1], 0.f);
    float ov2 = fmaxf(acc2 * inv + bias[c0 + 2], 0.f);
    float ov3 = fmaxf(acc3 * inv + bias[c0 + 3], 0.f);
    float p[5];
#pragma unroll
    for (int j = 0; j < 5; ++j) {
        p[j] = ov0 * fc_w[(c0 + 0) * 5 + j] + ov1 * fc_w[(c0 + 1) * 5 + j]
             + ov2 * fc_w[(c0 + 2) * 5 + j] + ov3 * fc_w[(c0 + 3) * 5 + j];
    }
#pragma unroll
    for (int off = 16; off >= 1; off >>= 1) {
#pragma unroll
        for (int j = 0; j < 5; ++j) p[j] += __shfl_xor(p[j], off);
    }
    if (q == 0) {
        float l[5], m = -1e30f;
#pragma unroll
        for (int j = 0; j < 5; ++j) { l[j] = p[j] + fc_b[j]; m = fmaxf(m, l[j]); }
        float sum = 0.f;
#pragma unroll
        for (int j = 0; j < 5; ++j) sum += __expf(l[j] - m);
        float ls = m + __logf(sum);
#pragma unroll
        for (int j = 0; j < 5; ++j) out[d * 5 + j] = l[j] - ls;
    }
}

extern "C" void kernel_launch(void* const* d_in, const int* in_sizes, int n_in,
                              void* d_out, int out_size, void* d_ws, size_t ws_size,
                              hipStream_t stream) {
    const float* x     = (const float*)d_in[0];
    const int*   ei    = (const int*)d_in[1];
    const float* W     = (const float*)d_in[2];
    const float* att_s = (const float*)d_in[3];
    const float* att_d = (const float*)d_in[4];
    const float* bias  = (const float*)d_in[5];
    const float* fc_w  = (const float*)d_in[6];
    const float* fc_b  = (const float*)d_in[7];
    float* out = (float*)d_out;

    char* ws = (char*)d_ws;
    size_t off = 0;
    auto carve = [&](size_t bytes) {
        void* p = ws + off;
        off = (off + bytes + 255) & ~(size_t)255;
        return p;
    };
    __hip_bfloat162* h = (__hip_bfloat162*)carve((size_t)N_NODES * HC * 2);
    float*    a_src   = (float*)   carve((size_t)N_NODES * HEADS * 4);
    float*    a_dst   = (float*)   carve((size_t)N_NODES * HEADS * 4);
    int*      cnt2d   = (int*)     carve((size_t)NCH * NB * 4);
    int*      etot    = (int*)     carve((NB + 1) * 4);
    int*      sbase   = (int*)     carve((NB + 1) * 4);
    int*      offsets = (int*)     carve((size_t)(N_NODES + 1) * 4);
    unsigned* stg     = (unsigned*)carve((size_t)N_EDGES * 4);
    int*      csr_src = (int*)     carve((size_t)TOTAL_E * 4);

    k_node<<<512, 256, 0, stream>>>(x, W, att_s, att_d, h, a_src, a_dst);
    k_hist2d<<<NCH, 256, 0, stream>>>(ei, cnt2d);
    k_scan_chunks<<<NB, 512, 0, stream>>>(cnt2d, etot);
    k_scan_top<<<1, 512, 0, stream>>>(etot, sbase, offsets);
    k_place<<<NCH, 256, 0, stream>>>(ei, cnt2d, sbase, stg);
    k_build<<<NB, 256, 0, stream>>>(stg, sbase, offsets, csr_src);
    k_gather<<<(N_NODES + 7) / 8, 256, 0, stream>>>(h, a_src, a_dst, offsets, csr_src,
                                                    bias, fc_w, fc_b, out);
}